// Round 4
// baseline (401.362 us; speedup 1.0000x reference)
//
#include <hip/hip_runtime.h>
#include <hip/hip_bf16.h>

#define S_SAMPLES 4096
#define NAG 16
#define STR 36   // shorts per LDS row: 72 B. 4q-row offset = 72q B -> banks {0,8,16,24},
                 // conflict-free scalar writes; 8B-aligned b64 reads.

typedef __attribute__((ext_vector_type(8))) short short8;   // 16x16x32 A/B frag
typedef __attribute__((ext_vector_type(4))) short short4v;  // 16x16x16 A/B frag
typedef __attribute__((ext_vector_type(4))) float f32x4;    // C/D frag

union F8 { short8 v; unsigned u[4]; };
union F4 { short4v v; unsigned u[2]; };

__device__ __forceinline__ float tanh_fast(float x) {
    float ax = fabsf(x);
    float e  = __expf(-2.0f * ax);
    float t  = (1.0f - e) * __builtin_amdgcn_rcpf(1.0f + e);
    return copysignf(t, x);
}

__device__ __forceinline__ unsigned pk2(float a, float b) {
    float2 f; f.x = a; f.y = b;
    __hip_bfloat162 h = __float22bfloat162_rn(f);
    unsigned r; __builtin_memcpy(&r, &h, 4); return r;
}

__device__ __forceinline__ short bfs(float a) {
    __hip_bfloat16 h = __float2bfloat16(a);
    short r; __builtin_memcpy(&r, &h, 2); return r;
}

__device__ __forceinline__ float4 ld4(const float* p) {
    return *reinterpret_cast<const float4*>(p);
}

// K=16 bf16 MFMA. Fallback zero-pads to 16x16x32: the k-relabeling (a[j]->k=8q+j)
// is applied consistently to BOTH operands, so the 16-term dot product is exact.
__device__ __forceinline__ f32x4 mfma_k16(short4v a, short4v b, f32x4 c) {
#if __has_builtin(__builtin_amdgcn_mfma_f32_16x16x16bf16_1k)
    return __builtin_amdgcn_mfma_f32_16x16x16bf16_1k(a, b, c, 0, 0, 0);
#else
    short8 a8 = { a[0], a[1], a[2], a[3], 0, 0, 0, 0 };
    short8 b8 = { b[0], b[1], b[2], b[3], 0, 0, 0, 0 };
    return __builtin_amdgcn_mfma_f32_16x16x32_bf16(a8, b8, c, 0, 0, 0);
#endif
}

#define WAVE_FENCE() __asm__ volatile("" ::: "memory")

__global__ __launch_bounds__(256, 3) void att_mask_kernel(
    const float* __restrict__ x, const float* __restrict__ L,
    const float* __restrict__ Aq, const float* __restrict__ Ak,
    const float* __restrict__ Av, const float* __restrict__ Ao,
    float* __restrict__ out)
{
    // Per-wave LDS only (wave-synchronous; no block barriers in the main loop)
    __shared__ alignas(16) short sQ[4][32 * STR];   // Q[r][n] row-major bf16
    __shared__ alignas(16) short sK[4][32 * STR];   // K[s][n] row-major bf16
    __shared__ alignas(16) float sRsq[16 * 17];

    const int tid  = threadIdx.x;
    const int lane = tid & 63;
    const int w    = tid >> 6;
    const int c4   = lane & 15;      // col / n index
    const int q    = lane >> 4;      // quad
    const int s_idx = blockIdx.x;

    short* qw = sQ[w];
    short* kw = sK[w];

    // ---- one-time: A-matrix 16x16x32 A-fragments, register-resident ----
    // aF[m][rh][kb]: lane holds Amat[r=c4+16rh][d=32kb+8q+j], j=0..7
    F8 aF[3][2][2];
    {
        const float* mats[3] = { Aq, Ak, Av };
        #pragma unroll
        for (int m = 0; m < 3; ++m)
            #pragma unroll
            for (int rh = 0; rh < 2; ++rh)
                #pragma unroll
                for (int kb = 0; kb < 2; ++kb) {
                    const float* p = mats[m] + (c4 + 16 * rh) * 64 + 32 * kb + 8 * q;
                    float4 a0 = ld4(p), a1 = ld4(p + 4);
                    aF[m][rh][kb].u[0] = pk2(a0.x, a0.y);
                    aF[m][rh][kb].u[1] = pk2(a0.z, a0.w);
                    aF[m][rh][kb].u[2] = pk2(a1.x, a1.y);
                    aF[m][rh][kb].u[3] = pk2(a1.z, a1.w);
                }
    }
    // Ao values for the o C-fragment rows r = 4q+reg+16rh
    float4 ao0 = ld4(Ao + 4 * q);
    float4 ao1 = ld4(Ao + 16 + 4 * q);

    const f32x4 zz = {0.f, 0.f, 0.f, 0.f};

    #pragma unroll
    for (int t = 0; t < 4; ++t) {
        const int i_loc = w * 4 + t;
        const int b     = s_idx * NAG + i_loc;

        // ---- num_neighbors ----
        float lv = (lane < 16) ? L[(size_t)b * 256 + lane] : 0.0f;
        unsigned long long ball = __ballot(lv >= 1.0f);
        float scale = rsqrtf((float)(__popcll(ball) + 1));

        // ---- x directly into 16x16x32 B-fragments: lane needs x[d=32kb+8q+j][n=c4] ----
        const float* xb = x + (size_t)b * 1024 + 128 * q + c4;
        float xv[2][8];
        #pragma unroll
        for (int kb = 0; kb < 2; ++kb)
            #pragma unroll
            for (int j = 0; j < 8; ++j)
                xv[kb][j] = xb[512 * kb + 16 * j];
        F8 bx[2];
        #pragma unroll
        for (int kb = 0; kb < 2; ++kb)
            #pragma unroll
            for (int p = 0; p < 4; ++p)
                bx[kb].u[p] = pk2(xv[kb][2 * p], xv[kb][2 * p + 1]);

        // ---- QKV: 12 MFMAs (16x16x32, K=d=64) ----
        f32x4 accQ[2], accK[2], accV[2];
        #pragma unroll
        for (int rh = 0; rh < 2; ++rh) {
            accQ[rh] = __builtin_amdgcn_mfma_f32_16x16x32_bf16(aF[0][rh][0].v, bx[0].v, zz, 0, 0, 0);
            accQ[rh] = __builtin_amdgcn_mfma_f32_16x16x32_bf16(aF[0][rh][1].v, bx[1].v, accQ[rh], 0, 0, 0);
            accK[rh] = __builtin_amdgcn_mfma_f32_16x16x32_bf16(aF[1][rh][0].v, bx[0].v, zz, 0, 0, 0);
            accK[rh] = __builtin_amdgcn_mfma_f32_16x16x32_bf16(aF[1][rh][1].v, bx[1].v, accK[rh], 0, 0, 0);
            accV[rh] = __builtin_amdgcn_mfma_f32_16x16x32_bf16(aF[2][rh][0].v, bx[0].v, zz, 0, 0, 0);
            accV[rh] = __builtin_amdgcn_mfma_f32_16x16x32_bf16(aF[2][rh][1].v, bx[1].v, accV[rh], 0, 0, 0);
        }

        // ---- tanh; Q,K -> LDS rows (conflict-free scalar b16); V stays in regs as
        //      16x16x16 B-frags: vB[sh][i] = V[4q+i+16sh][c4] ----
        WAVE_FENCE();
        F4 vB[2];
        #pragma unroll
        for (int rh = 0; rh < 2; ++rh) {
            float tq[4], tk[4], tv[4];
            #pragma unroll
            for (int r2 = 0; r2 < 4; ++r2) {
                tq[r2] = tanh_fast(accQ[rh][r2]);
                tk[r2] = tanh_fast(accK[rh][r2]);
                tv[r2] = tanh_fast(accV[rh][r2]);
            }
            #pragma unroll
            for (int r2 = 0; r2 < 4; ++r2) {
                int r = 4 * q + r2 + 16 * rh;
                qw[r * STR + c4] = bfs(tq[r2]);
                kw[r * STR + c4] = bfs(tk[r2]);
            }
            vB[rh].u[0] = pk2(tv[0], tv[1]);
            vB[rh].u[1] = pk2(tv[2], tv[3]);
        }
        WAVE_FENCE();   // wave-private LDS: DS ops are in-order within a wave; no s_barrier

        // ---- scoresT[s][r] = sum_n K[s][n] Q[r][n], K=16 (n exact, no pad) ----
        // A-frag: K[c4+16sh][4q+j]; B-frag: Q[c4+16rh2][4q+j] -> ds_read_b64
        short4v kA[2], qB[2];
        #pragma unroll
        for (int h = 0; h < 2; ++h) {
            kA[h] = *reinterpret_cast<const short4v*>(&kw[(c4 + 16 * h) * STR + 4 * q]);
            qB[h] = *reinterpret_cast<const short4v*>(&qw[(c4 + 16 * h) * STR + 4 * q]);
        }
        f32x4 sc[2][2];  // sc[sh][rh2][r2] = attn_pre[r=c4+16rh2][s=4q+r2+16sh]
        #pragma unroll
        for (int sh = 0; sh < 2; ++sh)
            #pragma unroll
            for (int rh2 = 0; rh2 < 2; ++rh2)
                sc[sh][rh2] = mfma_k16(kA[sh], qB[rh2], zz);

        // ---- softmax over s per row r (8 local + quad-group via xor16/xor32) ----
        #pragma unroll
        for (int rh2 = 0; rh2 < 2; ++rh2) {
            float v[8];
            #pragma unroll
            for (int sh = 0; sh < 2; ++sh)
                #pragma unroll
                for (int r2 = 0; r2 < 4; ++r2)
                    v[sh * 4 + r2] = sc[sh][rh2][r2] * scale;
            float mx = v[0];
            #pragma unroll
            for (int j2 = 1; j2 < 8; ++j2) mx = fmaxf(mx, v[j2]);
            mx = fmaxf(mx, __shfl_xor(mx, 16));
            mx = fmaxf(mx, __shfl_xor(mx, 32));
            float sum = 0.f;
            #pragma unroll
            for (int j2 = 0; j2 < 8; ++j2) { v[j2] = __expf(v[j2] - mx); sum += v[j2]; }
            sum += __shfl_xor(sum, 16);
            sum += __shfl_xor(sum, 32);
            float inv = __builtin_amdgcn_rcpf(sum);
            #pragma unroll
            for (int sh = 0; sh < 2; ++sh)
                #pragma unroll
                for (int r2 = 0; r2 < 4; ++r2)
                    sc[sh][rh2][r2] = v[sh * 4 + r2] * inv;
        }

        // ---- PV entirely in registers: attn is already the 16x16x16 A-frag,
        //      tanh(V) C-frag is already the B-frag ----
        f32x4 o[2];
        #pragma unroll
        for (int rh = 0; rh < 2; ++rh) {
            F4 aA0, aA1;
            aA0.u[0] = pk2(sc[0][rh][0], sc[0][rh][1]);
            aA0.u[1] = pk2(sc[0][rh][2], sc[0][rh][3]);
            aA1.u[0] = pk2(sc[1][rh][0], sc[1][rh][1]);
            aA1.u[1] = pk2(sc[1][rh][2], sc[1][rh][3]);
            o[rh] = mfma_k16(aA1.v, vB[1].v, mfma_k16(aA0.v, vB[0].v, zz));
        }

        // ---- R[n] = tanh(sum_r Ao[r] o[r][n]); lane rows r = 4q+reg+16rh ----
        float part = 0.f;
        part = fmaf(ao0.x, o[0][0], part); part = fmaf(ao0.y, o[0][1], part);
        part = fmaf(ao0.z, o[0][2], part); part = fmaf(ao0.w, o[0][3], part);
        part = fmaf(ao1.x, o[1][0], part); part = fmaf(ao1.y, o[1][1], part);
        part = fmaf(ao1.z, o[1][2], part); part = fmaf(ao1.w, o[1][3], part);
        part += __shfl_xor(part, 16);
        part += __shfl_xor(part, 32);
        if (lane < 16) {
            float tt = tanh_fast(part);
            sRsq[i_loc * 17 + lane] = tt * tt;
        }
    }

    __syncthreads();   // the only block barrier: sRsq is cross-wave

    // ---- Laplacian-like reconstruction ----
    {
        int i = tid >> 4, j = tid & 15;
        float rij = sRsq[i * 17 + j];
        float srow = 0.0f;
        #pragma unroll
        for (int k = 0; k < 16; ++k) srow += sRsq[i * 17 + k];
        out[(size_t)s_idx * 256 + tid] = (i == j) ? srow : -rij;
    }
}

extern "C" void kernel_launch(void* const* d_in, const int* in_sizes, int n_in,
                              void* d_out, int out_size, void* d_ws, size_t ws_size,
                              hipStream_t stream) {
    const float* x  = (const float*)d_in[0];
    const float* L  = (const float*)d_in[1];
    const float* Aq = (const float*)d_in[2];
    const float* Ak = (const float*)d_in[3];
    const float* Av = (const float*)d_in[4];
    const float* Ao = (const float*)d_in[5];
    float* out = (float*)d_out;

    dim3 grid(S_SAMPLES), block(256);
    hipLaunchKernelGGL(att_mask_kernel, grid, block, 0, stream,
                       x, L, Aq, Ak, Av, Ao, out);
}